// Round 2
// baseline (1308.521 us; speedup 1.0000x reference)
//
#include <hip/hip_runtime.h>

#define NE 1000000
#define NN 50000
#define D 64
#define NG (NE/4)    // 4-edge groups
#define NGN (NN/4)   // 4-node groups

// ---------------------------------------------------------------------------
// Fused: zero acc_y/denom + node GEMVs.
// 4 nodes per wave-iteration: lane loads float4 covering row r=lane>>4,
// cols 4*(lane&15)..+3; stage 1KB to LDS; per-node uniform b128 broadcast.
__global__ __launch_bounds__(256) void k_node(const float* __restrict__ x_v,
    const float* __restrict__ W_vv, const float* __restrict__ b_vv,
    const float* __restrict__ W_av, float* __restrict__ h_v,
    float* __restrict__ p_av, float4* __restrict__ acc4,
    float* __restrict__ denom){
  __shared__ float4 xs[4][2][64];
  // zero the atomic accumulators (k_edge runs after us; no race)
  int tid = blockIdx.x*256 + threadIdx.x;
  int nt  = gridDim.x*256;
  for (int i = tid; i < NN*D/4; i += nt) acc4[i] = make_float4(0.f,0.f,0.f,0.f);
  for (int i = tid; i < NN;     i += nt) denom[i] = 0.f;

  int lane = threadIdx.x & 63;
  int wv   = threadIdx.x >> 6;
  int wid  = __builtin_amdgcn_readfirstlane(blockIdx.x*4 + wv);
  int nw   = gridDim.x*4;
  float4 wvv[16], wav[16];
  #pragma unroll
  for (int q = 0; q < 16; q++){
    wvv[q] = *(const float4*)(W_vv + lane*D + q*4);
    wav[q] = *(const float4*)(W_av + lane*D + q*4);
  }
  float bv = b_vv[lane];
  int p = 0;
  for (int g = wid; g < NGN; g += nw, p ^= 1){
    int n0 = g*4;
    float4 xv = *(const float4*)(x_v + (size_t)n0*D + lane*4);
    xs[wv][p][lane] = xv;
    __builtin_amdgcn_wave_barrier();
    float A0=0.f,A1=0.f,A2=0.f,A3=0.f;   // h_self for nodes 0..3, col=lane
    float B0=0.f,B1=0.f,B2=0.f,B3=0.f;   // p_av
    #pragma unroll
    for (int q = 0; q < 16; q++){
      float4 x0 = xs[wv][p][q];
      float4 x1 = xs[wv][p][16+q];
      float4 x2 = xs[wv][p][32+q];
      float4 x3 = xs[wv][p][48+q];
      float4 wq = wvv[q], aq = wav[q];
      A0 += x0.x*wq.x + x0.y*wq.y + x0.z*wq.z + x0.w*wq.w;
      A1 += x1.x*wq.x + x1.y*wq.y + x1.z*wq.z + x1.w*wq.w;
      A2 += x2.x*wq.x + x2.y*wq.y + x2.z*wq.z + x2.w*wq.w;
      A3 += x3.x*wq.x + x3.y*wq.y + x3.z*wq.z + x3.w*wq.w;
      B0 += x0.x*aq.x + x0.y*aq.y + x0.z*aq.z + x0.w*aq.w;
      B1 += x1.x*aq.x + x1.y*aq.y + x1.z*aq.z + x1.w*aq.w;
      B2 += x2.x*aq.x + x2.y*aq.y + x2.z*aq.z + x2.w*aq.w;
      B3 += x3.x*aq.x + x3.y*aq.y + x3.z*aq.z + x3.w*aq.w;
    }
    h_v [(size_t)(n0+0)*D + lane] = A0 + bv;
    h_v [(size_t)(n0+1)*D + lane] = A1 + bv;
    h_v [(size_t)(n0+2)*D + lane] = A2 + bv;
    h_v [(size_t)(n0+3)*D + lane] = A3 + bv;
    p_av[(size_t)(n0+0)*D + lane] = B0;
    p_av[(size_t)(n0+1)*D + lane] = B1;
    p_av[(size_t)(n0+2)*D + lane] = B2;
    p_av[(size_t)(n0+3)*D + lane] = B3;
  }
}

// ---------------------------------------------------------------------------
// Fused edge pass, 4 edges per wave-iteration.
//   h_a[e] = x_a[e]@W_aa^T + b_aa + p_av[src] + p_av[dst]
//   w      = exp(x_a[e]·W_att + b_att)       (no max-sub: |logit| <~ 3.1)
//   denom[d] += w ; acc_y[d][:] += w*x_a[e]  (HW f32 atomics)
__global__ __launch_bounds__(256) void k_edge(const float* __restrict__ x_a,
    const int* __restrict__ src, const int* __restrict__ dst,
    const float* __restrict__ W_aa, const float* __restrict__ b_aa,
    const float* __restrict__ W_att, const float* __restrict__ b_att,
    const float* __restrict__ p_av, float* __restrict__ h_a,
    float* __restrict__ acc_y, float* __restrict__ denom){
  __shared__ float4 xs[4][2][64];
  int lane = threadIdx.x & 63;
  int wv   = threadIdx.x >> 6;
  int wid  = __builtin_amdgcn_readfirstlane(blockIdx.x*4 + wv);
  int nw   = gridDim.x*4;
  float4 waa[16];
  #pragma unroll
  for (int q = 0; q < 16; q++)
    waa[q] = *(const float4*)(W_aa + lane*D + q*4);   // W_aa[lane][4q..4q+3]
  float  ba   = b_aa[lane];
  float4 wt4  = *(const float4*)(W_att + (lane & 15)*4);
  float  batt = b_att[0];
  int r = lane >> 4;                 // this lane's x-chunk belongs to edge r

  int p = 0;
  for (int g = wid; g < NG; g += nw, p ^= 1){
    int e0 = g*4;
    int4 sv = *(const int4*)(src + e0);
    int4 dv = *(const int4*)(dst + e0);
    int s0 = __builtin_amdgcn_readfirstlane(sv.x);
    int s1 = __builtin_amdgcn_readfirstlane(sv.y);
    int s2 = __builtin_amdgcn_readfirstlane(sv.z);
    int s3 = __builtin_amdgcn_readfirstlane(sv.w);
    int d0 = __builtin_amdgcn_readfirstlane(dv.x);
    int d1 = __builtin_amdgcn_readfirstlane(dv.y);
    int d2 = __builtin_amdgcn_readfirstlane(dv.z);
    int d3 = __builtin_amdgcn_readfirstlane(dv.w);
    // 4 consecutive edge rows = 256 contiguous floats
    float4 xv = *(const float4*)(x_a + (size_t)e0*D + lane*4);
    // 8 independent gathers (col = lane), SGPR base + lane offset
    float ps0 = p_av[(size_t)s0*D + lane];
    float ps1 = p_av[(size_t)s1*D + lane];
    float ps2 = p_av[(size_t)s2*D + lane];
    float ps3 = p_av[(size_t)s3*D + lane];
    float pd0 = p_av[(size_t)d0*D + lane];
    float pd1 = p_av[(size_t)d1*D + lane];
    float pd2 = p_av[(size_t)d2*D + lane];
    float pd3 = p_av[(size_t)d3*D + lane];
    xs[wv][p][lane] = xv;
    __builtin_amdgcn_wave_barrier();
    // attention logit for edge r: partial dot then 16-lane-group butterfly
    float el = xv.x*wt4.x + xv.y*wt4.y + xv.z*wt4.z + xv.w*wt4.w;
    el += __shfl_xor(el, 1, 64);
    el += __shfl_xor(el, 2, 64);
    el += __shfl_xor(el, 4, 64);
    el += __shfl_xor(el, 8, 64);
    float w = __expf(el + batt);     // lane holds w of edge r
    // 4 GEMVs via uniform-broadcast b128 reads
    float A0=0.f,A1=0.f,A2=0.f,A3=0.f;
    #pragma unroll
    for (int q = 0; q < 16; q++){
      float4 x0 = xs[wv][p][q];
      float4 x1 = xs[wv][p][16+q];
      float4 x2 = xs[wv][p][32+q];
      float4 x3 = xs[wv][p][48+q];
      float4 wq = waa[q];
      A0 += x0.x*wq.x + x0.y*wq.y + x0.z*wq.z + x0.w*wq.w;
      A1 += x1.x*wq.x + x1.y*wq.y + x1.z*wq.z + x1.w*wq.w;
      A2 += x2.x*wq.x + x2.y*wq.y + x2.z*wq.z + x2.w*wq.w;
      A3 += x3.x*wq.x + x3.y*wq.y + x3.z*wq.z + x3.w*wq.w;
    }
    h_a[(size_t)(e0+0)*D + lane] = A0 + ba + ps0 + pd0;
    h_a[(size_t)(e0+1)*D + lane] = A1 + ba + ps1 + pd1;
    h_a[(size_t)(e0+2)*D + lane] = A2 + ba + ps2 + pd2;
    h_a[(size_t)(e0+3)*D + lane] = A3 + ba + ps3 + pd3;
    // acc_y: lane covers cols 4*(lane&15).. of edge r's dst row
    int dsel = (r == 0) ? d0 : (r == 1) ? d1 : (r == 2) ? d2 : d3;
    float* ap = acc_y + (size_t)dsel*D + (lane & 15)*4;
    unsafeAtomicAdd(ap+0, w*xv.x);
    unsafeAtomicAdd(ap+1, w*xv.y);
    unsafeAtomicAdd(ap+2, w*xv.z);
    unsafeAtomicAdd(ap+3, w*xv.w);
    if ((lane & 15) == 0) unsafeAtomicAdd(&denom[dsel], w);
  }
}

// ---------------------------------------------------------------------------
// h_v[n] += W_va @ (acc_y[n] / denom[n]) ; 4 nodes per wave-iteration
__global__ __launch_bounds__(256) void k_finish(const float* __restrict__ acc_y,
    const float* __restrict__ denom, const float* __restrict__ W_va,
    float* __restrict__ h_v){
  __shared__ float4 ys[4][2][64];
  int lane = threadIdx.x & 63;
  int wv   = threadIdx.x >> 6;
  int wid  = __builtin_amdgcn_readfirstlane(blockIdx.x*4 + wv);
  int nw   = gridDim.x*4;
  float4 wva[16];
  #pragma unroll
  for (int q = 0; q < 16; q++)
    wva[q] = *(const float4*)(W_va + lane*D + q*4);
  int r = lane >> 4;
  int p = 0;
  for (int g = wid; g < NGN; g += nw, p ^= 1){
    int n0 = g*4;
    float4 dn = *(const float4*)(denom + n0);
    float4 yv = *(const float4*)(acc_y + (size_t)n0*D + lane*4);
    float dsel = (r == 0) ? dn.x : (r == 1) ? dn.y : (r == 2) ? dn.z : dn.w;
    float inv  = (dsel > 0.f) ? 1.f/dsel : 0.f;   // empty segment -> zero msg
    yv.x *= inv; yv.y *= inv; yv.z *= inv; yv.w *= inv;
    ys[wv][p][lane] = yv;
    __builtin_amdgcn_wave_barrier();
    float A0=0.f,A1=0.f,A2=0.f,A3=0.f;
    #pragma unroll
    for (int q = 0; q < 16; q++){
      float4 y0 = ys[wv][p][q];
      float4 y1 = ys[wv][p][16+q];
      float4 y2 = ys[wv][p][32+q];
      float4 y3 = ys[wv][p][48+q];
      float4 wq = wva[q];
      A0 += y0.x*wq.x + y0.y*wq.y + y0.z*wq.z + y0.w*wq.w;
      A1 += y1.x*wq.x + y1.y*wq.y + y1.z*wq.z + y1.w*wq.w;
      A2 += y2.x*wq.x + y2.y*wq.y + y2.z*wq.z + y2.w*wq.w;
      A3 += y3.x*wq.x + y3.y*wq.y + y3.z*wq.z + y3.w*wq.w;
    }
    h_v[(size_t)(n0+0)*D + lane] += A0;
    h_v[(size_t)(n0+1)*D + lane] += A1;
    h_v[(size_t)(n0+2)*D + lane] += A2;
    h_v[(size_t)(n0+3)*D + lane] += A3;
  }
}

// ---------------------------------------------------------------------------
extern "C" void kernel_launch(void* const* d_in, const int* in_sizes, int n_in,
                              void* d_out, int out_size, void* d_ws, size_t ws_size,
                              hipStream_t stream){
  const float* x_v   = (const float*)d_in[0];
  const float* x_a   = (const float*)d_in[1];
  const int*   arc   = (const int*)  d_in[2];
  const float* W_vv  = (const float*)d_in[3];
  const float* b_vv  = (const float*)d_in[4];
  const float* W_va  = (const float*)d_in[5];
  const float* W_att = (const float*)d_in[6];
  const float* b_att = (const float*)d_in[7];
  const float* W_aa  = (const float*)d_in[8];
  const float* b_aa  = (const float*)d_in[9];
  const float* W_av  = (const float*)d_in[10];

  float* out = (float*)d_out;
  float* h_v = out;                         // [NN, D]
  float* h_a = out + (size_t)NN*D;          // [NE, D]

  // workspace: acc_y[NN*D] | denom[NN] | p_av[NN*D]   (~25.8 MB)
  float* wsf   = (float*)d_ws;
  float* acc_y = wsf;
  float* denom = wsf + (size_t)NN*D;
  float* p_av  = wsf + (size_t)NN*D + NN;

  const int* srcp = arc;
  const int* dstp = arc + NE;

  hipLaunchKernelGGL(k_node,   dim3(1024), dim3(256), 0, stream,
                     x_v, W_vv, b_vv, W_av, h_v, p_av, (float4*)acc_y, denom);
  hipLaunchKernelGGL(k_edge,   dim3(2048), dim3(256), 0, stream,
                     x_a, srcp, dstp, W_aa, b_aa, W_att, b_att, p_av, h_a,
                     acc_y, denom);
  hipLaunchKernelGGL(k_finish, dim3(1024), dim3(256), 0, stream,
                     acc_y, denom, W_va, h_v);
}